// Round 1
// baseline (1238.009 us; speedup 1.0000x reference)
//
#include <hip/hip_runtime.h>
#include <hip/hip_bf16.h>

// Problem constants (B=8, N=4096, M=N/4, K=64, C_in=64, h=128)
#define BB   8
#define NN   4096
#define MM   1024
#define KK   64
#define CIN  64
#define HH   128

// f32 radius^2 predicate: largest f32 <= 0.2*0.2 (f64) = 0x3D23D70A.
#define R2F 0.039999999105930328f

// Inputs: f32, dict order. Output: f32, values bf16-rounded (matches np ref).
static __device__ __forceinline__ float rnd_bf16(float v) {
    return __bfloat162float(__float2bfloat16(v));
}
// Manual RNE f32->bf16 (finite inputs only; matches RNE for our h2 values).
static __device__ __forceinline__ unsigned int bf16bits(float v) {
    unsigned int u = __float_as_uint(v);
    return (u + 0x7FFFu + ((u >> 16) & 1u)) >> 16;
}

// Packed fp32 ops (VOP3P, gfx90a+). Inline asm: guarantees plain RN mul/add
// (no fma contraction) -> bit-exact np order (dx*dx + dy*dy) + dz*dz.
typedef float f32x2 __attribute__((ext_vector_type(2)));
static __device__ __forceinline__ f32x2 pk_add(f32x2 a, f32x2 b) {
    f32x2 r;
    asm("v_pk_add_f32 %0, %1, %2" : "=v"(r) : "v"(a), "v"(b));
    return r;
}
static __device__ __forceinline__ f32x2 pk_mul(f32x2 a, f32x2 b) {
    f32x2 r;
    asm("v_pk_mul_f32 %0, %1, %2" : "=v"(r) : "v"(a), "v"(b));
    return r;
}

// ---------------------------------------------------------------------------
// Kernel 1: FPS. Ledger: R11 base=631 (256thr, 256-lane same-addr LDS
// atomicMax ~260cy). R12 512thr=790, R13 4-slot+f4=694, R15 shfl-butterfly
// =1068 (ds_permute ~100cy each -- DO NOT use shuffles for the reduce).
// R16 (this): (a) v_pk_add/mul_f32 distance math (2 pts/inst, exact RN),
// (b) contiguous-range argmax TREE (depth 4, >= keeps left = first
// occurrence, same semantics as strict-> linear scan), (c) per-WAVE atomic
// slots (4 x 64-lane same-addr atomics in parallel banks ~65cy instead of
// one 256-lane ~260cy) + post-barrier register reduce of 4 keys,
// (d) float4-packed coord broadcast (1 ds_read_b128 instead of 3 reads).
// Key = (bits(d)<<32) | ~idx: u64 max == largest d, ties -> smallest idx
// (= np.argmax first-occurrence; d >= 0 so IEEE bits monotone).
// Slot reset uses the proven (j+2)&3 rotate, now 4 sets x 4 wave-slots.
// ---------------------------------------------------------------------------
__global__ __launch_bounds__(256) void fps_kernel(
    const float* __restrict__ pts,            // [B,3,N] f32
    float* __restrict__ centf,                // ws [B,M,3] f32 (exact)
    float* __restrict__ outc)                 // d_out (first B*M*3), f32
{
    const int b = blockIdx.x;
    const int t = threadIdx.x;
    __shared__ float4 lp[NN];                 // 64 KB packed coords
    __shared__ unsigned long long akey[16];   // 4 sets x 4 wave-slots

    const float* px = pts + (size_t)b * 3 * NN;
    f32x2 x2[8], y2[8], z2[8];
    float mind[16];
    {
        float xx[16], yy[16], zz[16];
#pragma unroll
        for (int i = 0; i < 16; ++i) {
            int p = t + i * 256;              // coalesced
            xx[i] = px[p];
            yy[i] = px[NN + p];
            zz[i] = px[2 * NN + p];
            lp[p] = make_float4(xx[i], yy[i], zz[i], 0.f);
            mind[i] = 3.4e38f;
        }
#pragma unroll
        for (int p = 0; p < 8; ++p) {
            x2[p].x = xx[2 * p]; x2[p].y = xx[2 * p + 1];
            y2[p].x = yy[2 * p]; y2[p].y = yy[2 * p + 1];
            z2[p].x = zz[2 * p]; z2[p].y = zz[2 * p + 1];
        }
    }
    if (t < 16) akey[t] = 0ULL;
    __syncthreads();

    float bx = lp[0].x, by = lp[0].y, bz = lp[0].z;
    const int wv = t >> 6;
    const bool wlead = (t & 63) == 0;

    for (int j = 0; j < MM; ++j) {
        if (t == 0) {
            int o = (b * MM + j) * 3;
            centf[o]    = bx; centf[o + 1] = by; centf[o + 2] = bz;
            outc[o]     = rnd_bf16(bx);
            outc[o + 1] = rnd_bf16(by);
            outc[o + 2] = rnd_bf16(bz);
        }
        // reset the set consumed 2 iterations ago (race-free: every wave
        // has passed >= 2 barriers since anyone read it)
        if (wlead) akey[((j + 2) & 3) * 4 + wv] = 0ULL;

        f32x2 nx2, ny2, nz2;
        { float n = -bx; nx2.x = n; nx2.y = n; }
        { float n = -by; ny2.x = n; ny2.y = n; }
        { float n = -bz; nz2.x = n; nz2.y = n; }

        float vd[16]; int vi[16];
#pragma unroll
        for (int p = 0; p < 8; ++p) {
            // exact np order per point: (dx*dx + dy*dy) + dz*dz, RN, no fma
            f32x2 dx = pk_add(x2[p], nx2);
            f32x2 dy = pk_add(y2[p], ny2);
            f32x2 dz = pk_add(z2[p], nz2);
            f32x2 s  = pk_add(pk_mul(dx, dx), pk_mul(dy, dy));
            f32x2 d2 = pk_add(s, pk_mul(dz, dz));
            float m0 = fminf(mind[2 * p],     d2.x);
            float m1 = fminf(mind[2 * p + 1], d2.y);
            mind[2 * p] = m0; mind[2 * p + 1] = m1;
            vd[2 * p] = m0;  vd[2 * p + 1] = m1;
            vi[2 * p]     = t + (2 * p) * 256;
            vi[2 * p + 1] = t + (2 * p + 1) * 256;
        }
        // contiguous-range max tree; >= keeps left = smallest index on ties
        // (left subtree holds strictly smaller global indices at every level)
#pragma unroll
        for (int s = 1; s < 16; s <<= 1)
#pragma unroll
            for (int i = 0; i < 16; i += 2 * s)
                if (!(vd[i] >= vd[i + s])) { vd[i] = vd[i + s]; vi[i] = vi[i + s]; }

        unsigned long long key =
            ((unsigned long long)__float_as_uint(vd[0]) << 32) |
            (unsigned long long)(0xFFFFFFFFu - (unsigned)vi[0]);
        atomicMax(&akey[(j & 3) * 4 + wv], key);
        __syncthreads();

        const int sb = (j & 3) * 4;
        unsigned long long k0 = akey[sb],     k1 = akey[sb + 1];
        unsigned long long k2 = akey[sb + 2], k3 = akey[sb + 3];
        unsigned long long m01 = k0 >= k1 ? k0 : k1;
        unsigned long long m23 = k2 >= k3 ? k2 : k3;
        unsigned long long bk  = m01 >= m23 ? m01 : m23;
        int best = (int)(0xFFFFFFFFu - (unsigned)(bk & 0xFFFFFFFFULL));
        float4 c = lp[best];
        bx = c.x; by = c.y; bz = c.z;
    }
}

// ---------------------------------------------------------------------------
// Kernel 2: per-point feature MLP cache. bf16 output EXACT under group max
// (RNE monotone). ~20us, not a bottleneck.
// ---------------------------------------------------------------------------
__global__ __launch_bounds__(256) void featmlp_kernel(
    const float* __restrict__ feat,            // [B,CIN,N] f32
    const float* __restrict__ fw1, const float* __restrict__ fb1,
    const float* __restrict__ fw2, const float* __restrict__ fb2,
    const float* __restrict__ fw3, const float* __restrict__ fb3,
    __hip_bfloat16* __restrict__ out)          // ws [B,N,HH] bf16
{
    __shared__ float w1[CIN * CIN], w2[CIN * CIN];
    const int tid = threadIdx.x;
    for (int i = tid; i < CIN * CIN; i += 256) { w1[i] = fw1[i]; w2[i] = fw2[i]; }
    __syncthreads();

    const int gid = blockIdx.x * 256 + tid;    // b*N + n
    const int b = gid >> 12, n = gid & (NN - 1);
    const float* fp = feat + (size_t)b * CIN * NN + n;

    float f[CIN];
#pragma unroll
    for (int c = 0; c < CIN; ++c) f[c] = fp[(size_t)c * NN];

    float h1[CIN];
    for (int o = 0; o < CIN; ++o) {
        float acc = fb1[o];
#pragma unroll
        for (int c = 0; c < CIN; ++c) acc = fmaf(f[c], w1[o * CIN + c], acc);
        h1[o] = fmaxf(acc, 0.f);
    }
    float h2[CIN];
    for (int o = 0; o < CIN; ++o) {
        float acc = fb2[o];
#pragma unroll
        for (int c = 0; c < CIN; ++c) acc = fmaf(h1[c], w2[o * CIN + c], acc);
        h2[o] = fmaxf(acc, 0.f);
    }
    __hip_bfloat16* op = out + (size_t)gid * HH;
    for (int o = 0; o < HH; ++o) {
        float acc = fb3[o];
#pragma unroll
        for (int c = 0; c < CIN; ++c) acc = fmaf(h2[c], fw3[o * CIN + c], acc);
        op[o] = __float2bfloat16(acc);
    }
}

// ---------------------------------------------------------------------------
// Kernel 3: fused ball-query + point MLP + max + feature gather-max.
// vs R14: h2s stored as PACKED BF16 (u32 pairs, row stride 36 u32 = 144B,
// 16B-aligned) -> LDS 17.7KB -> 9.5KB -> occupancy ~9 -> ~16 blocks/CU.
// groupnet was latency-bound at 22% issue efficiency; occupancy is the lever.
// h2 bf16-rounding adds ~0.013 abs error to point-path outputs (threshold
// >= 0.05) -- discrete selections and feature path untouched.
// Phase 2 now runs 8 parallel accumulator chains (was 4).
// ---------------------------------------------------------------------------
#define H2SU 36   // u32 stride per k-row (32 data + 4 pad, 16B aligned)
__global__ __launch_bounds__(64) void groupnet_kernel(
    const float* __restrict__ pts,             // [B,3,N] f32
    const float* __restrict__ centf,           // ws [B,M,3] f32
    const __hip_bfloat16* __restrict__ fout,   // ws [B,N,HH] bf16
    const float* __restrict__ pw1, const float* __restrict__ pb1,
    const float* __restrict__ pw2, const float* __restrict__ pb2,
    const float* __restrict__ pw3, const float* __restrict__ pb3,
    float* __restrict__ outf)                  // d_out + B*M*3: [B,256,M] f32
{
    __shared__ unsigned int h2s[KK * H2SU];    // packed bf16 pairs, 9.2KB
    __shared__ int sels[KK];

    const int g = blockIdx.x;                  // b*M + m
    const int b = g >> 10, m = g & (MM - 1);
    const int lane = threadIdx.x;

    const float* pts_b = pts + (size_t)b * 3 * NN;
    const float cx = centf[(size_t)g * 3];
    const float cy = centf[(size_t)g * 3 + 1];
    const float cz = centf[(size_t)g * 3 + 2];

    // ---- 1) ball query: fixed 64 chunks, 2-stage software pipeline ----
    int cnt = 0, first = 0;
    bool have_first = false;
    float vx = pts_b[lane], vy = pts_b[NN + lane], vz = pts_b[2 * NN + lane];
    for (int base = 0; base < NN; base += 64) {
        float nx = 0.f, ny = 0.f, nz = 0.f;
        if (base + 64 < NN) {                  // prefetch next chunk
            int p = base + 64 + lane;
            nx = pts_b[p]; ny = pts_b[NN + p]; nz = pts_b[2 * NN + p];
        }
        float dx = vx - cx, dy = vy - cy, dz = vz - cz;
        float d2 = __fadd_rn(__fadd_rn(__fmul_rn(dx, dx), __fmul_rn(dy, dy)),
                             __fmul_rn(dz, dz));
        bool in = (d2 <= R2F);
        unsigned long long mask = __ballot(in);
        if (!have_first && mask != 0ULL) {
            first = base + (int)__builtin_ctzll(mask);
            have_first = true;
        }
        int pos = cnt + (int)__popcll(mask & ((1ULL << lane) - 1ULL));
        if (in && pos < KK) sels[pos] = base + lane;
        cnt += (int)__popcll(mask);
        vx = nx; vy = ny; vz = nz;
    }
    if (cnt < KK) {
        for (int q = cnt + lane; q < KK; q += 64) sels[q] = first;
    }
    __syncthreads();                           // sels visible

    const int s = sels[lane];
    float* ob = outf + (size_t)b * 256 * MM + m;

    // ---- 2) point path layers 1-2 (lane = slot k); 8 parallel chains ----
    {
        const float x = pts_b[s]          - cx;
        const float y = pts_b[NN + s]     - cy;
        const float z = pts_b[2 * NN + s] - cz;
        float h1[CIN];
#pragma unroll
        for (int o = 0; o < CIN; ++o) {
            float acc = pb1[o];
            acc = fmaf(x, pw1[o * 3 + 0], acc);
            acc = fmaf(y, pw1[o * 3 + 1], acc);
            acc = fmaf(z, pw1[o * 3 + 2], acc);
            h1[o] = fmaxf(acc, 0.f);
        }
        for (int o8 = 0; o8 < CIN / 8; ++o8) { // 8 outputs per iter
            float a[8];
#pragma unroll
            for (int q = 0; q < 8; ++q) a[q] = pb2[o8 * 8 + q];
            for (int c = 0; c < CIN; ++c) {
                float hc = h1[c];
#pragma unroll
                for (int q = 0; q < 8; ++q)
                    a[q] = fmaf(hc, pw2[(o8 * 8 + q) * CIN + c], a[q]);
            }
            uint4 pk;
            pk.x = bf16bits(fmaxf(a[0], 0.f)) | (bf16bits(fmaxf(a[1], 0.f)) << 16);
            pk.y = bf16bits(fmaxf(a[2], 0.f)) | (bf16bits(fmaxf(a[3], 0.f)) << 16);
            pk.z = bf16bits(fmaxf(a[4], 0.f)) | (bf16bits(fmaxf(a[5], 0.f)) << 16);
            pk.w = bf16bits(fmaxf(a[6], 0.f)) | (bf16bits(fmaxf(a[7], 0.f)) << 16);
            *(uint4*)&h2s[lane * H2SU + o8 * 4] = pk;
        }
    }
    __syncthreads();

    // ---- 3) point layer 3 + group max -> out ch 128..255 (k-split ILP) ----
    {
        float w3a[CIN], w3b[CIN];
#pragma unroll
        for (int c = 0; c < CIN; ++c) {
            w3a[c] = pw3[(size_t)lane * CIN + c];
            w3b[c] = pw3[(size_t)(lane + 64) * CIN + c];
        }
        const float b3a = pb3[lane], b3b = pb3[lane + 64];
        float pa0 = -3.4e38f, pb0 = -3.4e38f;  // k in [0,32)
        float pa1 = -3.4e38f, pb1v = -3.4e38f; // k in [32,64)
        for (int k = 0; k < KK / 2; ++k) {
            float va0 = b3a, vb0 = b3b, va1 = b3a, vb1 = b3b;
#pragma unroll
            for (int u4 = 0; u4 < 8; ++u4) {   // 8 uint4 = 32 u32 = 64 bf16
                uint4 p0 = *(const uint4*)&h2s[k * H2SU + u4 * 4];
                uint4 p1 = *(const uint4*)&h2s[(k + 32) * H2SU + u4 * 4];
                const unsigned int* w0 = &p0.x;
                const unsigned int* w1 = &p1.x;
#pragma unroll
                for (int j = 0; j < 4; ++j) {
                    int c = u4 * 8 + j * 2;
                    float h0lo = __uint_as_float(w0[j] << 16);
                    float h0hi = __uint_as_float(w0[j] & 0xFFFF0000u);
                    float h1lo = __uint_as_float(w1[j] << 16);
                    float h1hi = __uint_as_float(w1[j] & 0xFFFF0000u);
                    va0 = fmaf(h0lo, w3a[c],     va0); vb0 = fmaf(h0lo, w3b[c],     vb0);
                    va1 = fmaf(h1lo, w3a[c],     va1); vb1 = fmaf(h1lo, w3b[c],     vb1);
                    va0 = fmaf(h0hi, w3a[c + 1], va0); vb0 = fmaf(h0hi, w3b[c + 1], vb0);
                    va1 = fmaf(h1hi, w3a[c + 1], va1); vb1 = fmaf(h1hi, w3b[c + 1], vb1);
                }
            }
            pa0 = fmaxf(pa0, va0); pb0  = fmaxf(pb0,  vb0);
            pa1 = fmaxf(pa1, va1); pb1v = fmaxf(pb1v, vb1);
        }
        ob[(size_t)(128 + lane) * MM] = rnd_bf16(fmaxf(pa0, pa1));
        ob[(size_t)(192 + lane) * MM] = rnd_bf16(fmaxf(pb0, pb1v));
    }

    // ---- 4) feature gather-max (bf16 cache), k-split -> out ch 0..127 ----
    {
        const __hip_bfloat16* fb_ = fout + (size_t)b * NN * HH;
        float fa0 = -3.4e38f, fb0 = -3.4e38f;
        float fa1 = -3.4e38f, fb1v = -3.4e38f;
        for (int k = 0; k < KK / 2; ++k) {
            const __hip_bfloat16* fp0 = fb_ + (size_t)sels[k] * HH;
            const __hip_bfloat16* fp1 = fb_ + (size_t)sels[k + 32] * HH;
            fa0  = fmaxf(fa0,  __bfloat162float(fp0[lane]));
            fb0  = fmaxf(fb0,  __bfloat162float(fp0[lane + 64]));
            fa1  = fmaxf(fa1,  __bfloat162float(fp1[lane]));
            fb1v = fmaxf(fb1v, __bfloat162float(fp1[lane + 64]));
        }
        ob[(size_t)lane * MM]        = fmaxf(fa0, fa1);  // values already bf16-exact
        ob[(size_t)(lane + 64) * MM] = fmaxf(fb0, fb1v);
    }
}

extern "C" void kernel_launch(void* const* d_in, const int* in_sizes, int n_in,
                              void* d_out, int out_size, void* d_ws, size_t ws_size,
                              hipStream_t stream) {
    const float* pts  = (const float*)d_in[0];
    const float* feat = (const float*)d_in[1];
    const float* pw1  = (const float*)d_in[2];
    const float* pb1  = (const float*)d_in[3];
    const float* pw2  = (const float*)d_in[4];
    const float* pb2  = (const float*)d_in[5];
    const float* pw3  = (const float*)d_in[6];
    const float* pb3  = (const float*)d_in[7];
    const float* fw1  = (const float*)d_in[8];
    const float* fb1  = (const float*)d_in[9];
    const float* fw2  = (const float*)d_in[10];
    const float* fb2  = (const float*)d_in[11];
    const float* fw3  = (const float*)d_in[12];
    const float* fb3  = (const float*)d_in[13];

    float* out = (float*)d_out;                // f32 output

    // ws: [0,96KB) f32 centroids; [96KB, +8.39MB) bf16 feature-MLP cache.
    float* centf = (float*)d_ws;
    __hip_bfloat16* fout = (__hip_bfloat16*)((char*)d_ws + (size_t)BB * MM * 3 * 4);

    featmlp_kernel<<<(BB * NN) / 256, 256, 0, stream>>>(
        feat, fw1, fb1, fw2, fb2, fw3, fb3, fout);
    fps_kernel<<<BB, 256, 0, stream>>>(pts, centf, out);
    groupnet_kernel<<<BB * MM, 64, 0, stream>>>(
        pts, centf, fout,
        pw1, pb1, pw2, pb2, pw3, pb3,
        out + (size_t)BB * MM * 3);
}

// Round 2
// 971.259 us; speedup vs baseline: 1.2746x; 1.2746x over previous
//
#include <hip/hip_runtime.h>
#include <hip/hip_bf16.h>

// Problem constants (B=8, N=4096, M=N/4, K=64, C_in=64, h=128)
#define BB   8
#define NN   4096
#define MM   1024
#define KK   64
#define CIN  64
#define HH   128

// f32 radius^2 predicate: largest f32 <= 0.2*0.2 (f64) = 0x3D23D70A.
#define R2F 0.039999999105930328f

// Inputs: f32, dict order. Output: f32, values bf16-rounded (matches np ref).
static __device__ __forceinline__ float rnd_bf16(float v) {
    return __bfloat162float(__float2bfloat16(v));
}
// Manual RNE f32->bf16 (finite inputs only; matches RNE for our h2 values).
static __device__ __forceinline__ unsigned int bf16bits(float v) {
    unsigned int u = __float_as_uint(v);
    return (u + 0x7FFFu + ((u >> 16) & 1u)) >> 16;
}

// ---------------------------------------------------------------------------
// Kernel 1 (merged): FPS (blocks 0..7, EXACT R11 body) + featmlp
// (blocks 8..135) running concurrently on otherwise-idle CUs.
// FPS ledger: R11 base=631us (PROVEN floor config). R12 512thr=790.
// R13 4-slot+f4=694. R15 shfl-butterfly=1068 (ds_permute ~100cy each).
// R16 pk-asm+tree+4x64atomic=772 REGRESSED: SQ_LDS_BANK_CONFLICT identical
// (1966080) proved 4x64-lane atomics serialize same as 1x256-lane; pk
// inline-asm added VGPR-pair marshalling (+20 VGPR); u64 register reduce
// lengthened the serial tail. DO NOT re-try shuffles, pk-asm, or atomic
// slot-splitting here. 256-lane same-addr LDS atomicMax (~260cy) + strict->
// linear scan is the proven minimum.
// Key = (bits(d)<<32) | ~idx: u64 max == largest d, ties -> smallest idx
// (= np.argmax first-occurrence; d >= 0 so IEEE bits monotone).
// ---------------------------------------------------------------------------
__global__ __launch_bounds__(256) void fps_featmlp_kernel(
    const float* __restrict__ pts,            // [B,3,N] f32
    float* __restrict__ centf,                // ws [B,M,3] f32 (exact)
    float* __restrict__ outc,                 // d_out (first B*M*3), f32
    const float* __restrict__ feat,           // [B,CIN,N] f32
    const float* __restrict__ fw1, const float* __restrict__ fb1,
    const float* __restrict__ fw2, const float* __restrict__ fb2,
    const float* __restrict__ fw3, const float* __restrict__ fb3,
    __hip_bfloat16* __restrict__ fout)        // ws [B,N,HH] bf16
{
    __shared__ float smem[3 * NN];            // fps: lx/ly/lz; featmlp: w1/w2
    __shared__ unsigned long long akey[4];
    const int t = threadIdx.x;

    if (blockIdx.x < BB) {
        // ================= FPS path (EXACT R11 body) =================
        const int b = blockIdx.x;
        float* lx = smem;
        float* ly = smem + NN;
        float* lz = smem + 2 * NN;

        const float* px = pts + (size_t)b * 3 * NN;
        float x[16], y[16], z[16], mind[16];
#pragma unroll
        for (int i = 0; i < 16; ++i) {
            int p = t + i * 256;              // coalesced
            x[i] = px[p];
            y[i] = px[NN + p];
            z[i] = px[2 * NN + p];
            lx[p] = x[i]; ly[p] = y[i]; lz[p] = z[i];
            mind[i] = 3.4e38f;
        }
        if (t < 4) akey[t] = 0ULL;
        __syncthreads();

        float bx = lx[0], by = ly[0], bz = lz[0];

        for (int j = 0; j < MM; ++j) {
            if (t == 0) {
                int o = (b * MM + j) * 3;
                centf[o]    = bx; centf[o + 1] = by; centf[o + 2] = bz;
                outc[o]     = rnd_bf16(bx);
                outc[o + 1] = rnd_bf16(by);
                outc[o + 2] = rnd_bf16(bz);
                akey[(j + 2) & 3] = 0ULL;     // reset future slot (race-free)
            }
            float bd = -1.0f; int bi = 0;
#pragma unroll
            for (int i = 0; i < 16; ++i) {
                float dx = x[i] - bx, dy = y[i] - by, dz = z[i] - bz;
                // exact np order: (dx*dx + dy*dy) + dz*dz, RN, no fma
                float d = __fadd_rn(__fadd_rn(__fmul_rn(dx, dx), __fmul_rn(dy, dy)),
                                    __fmul_rn(dz, dz));
                float md = fminf(mind[i], d);
                mind[i] = md;
                if (md > bd) { bd = md; bi = t + i * 256; }  // strict >: smaller idx
            }
            unsigned long long key =
                ((unsigned long long)__float_as_uint(bd) << 32) |
                (unsigned long long)(0xFFFFFFFFu - (unsigned)bi);
            atomicMax(&akey[j & 3], key);
            __syncthreads();
            unsigned long long bk = akey[j & 3];
            int best = (int)(0xFFFFFFFFu - (unsigned)(bk & 0xFFFFFFFFULL));
            bx = lx[best]; by = ly[best]; bz = lz[best];
        }
    } else {
        // ================= featmlp path =================
        float* w1 = smem;
        float* w2 = smem + CIN * CIN;
        for (int i = t; i < CIN * CIN; i += 256) { w1[i] = fw1[i]; w2[i] = fw2[i]; }
        __syncthreads();

        const int gid = (blockIdx.x - BB) * 256 + t;   // b*N + n
        const int b = gid >> 12, n = gid & (NN - 1);
        const float* fp = feat + (size_t)b * CIN * NN + n;

        float f[CIN];
#pragma unroll
        for (int c = 0; c < CIN; ++c) f[c] = fp[(size_t)c * NN];

        float h1[CIN];
        for (int o = 0; o < CIN; ++o) {
            float acc = fb1[o];
#pragma unroll
            for (int c = 0; c < CIN; ++c) acc = fmaf(f[c], w1[o * CIN + c], acc);
            h1[o] = fmaxf(acc, 0.f);
        }
        float h2[CIN];
        for (int o = 0; o < CIN; ++o) {
            float acc = fb2[o];
#pragma unroll
            for (int c = 0; c < CIN; ++c) acc = fmaf(h1[c], w2[o * CIN + c], acc);
            h2[o] = fmaxf(acc, 0.f);
        }
        __hip_bfloat16* op = fout + (size_t)gid * HH;
        for (int o = 0; o < HH; ++o) {
            float acc = fb3[o];
#pragma unroll
            for (int c = 0; c < CIN; ++c) acc = fmaf(h2[c], fw3[o * CIN + c], acc);
            op[o] = __float2bfloat16(acc);
        }
    }
}

// ---------------------------------------------------------------------------
// Kernel 3: fused ball-query + point MLP + max + feature gather-max.
// R17 changes vs R14 (latency-bound, <10% issue efficiency at ~430us;
// issue-bound floor ~25-50us):
//  (a) ball query: 4-deep software-pipelined loads (was 1-deep; L2 hit
//      ~200cy vs ~50cy of per-iter work -> ~150cy stall/iter removed).
//      Static prefetch-ring indices via full inner unroll (rule #20).
//  (b) phase 4: u32 loads (bf16 pair; lane owns channels 2L,2L+1) -> 2
//      coalesced 256B row loads per k instead of 4, with a 4-deep prefetch
//      ring + 4 independent fmax chains. Max over identical row set ->
//      bit-exact.
// h2 bf16-rounding (phase 2/3) adds ~0.013 abs error to point-path outputs
// (threshold >= 0.05) -- discrete selections and feature path untouched.
// ---------------------------------------------------------------------------
#define H2SU 36   // u32 stride per k-row (32 data + 4 pad, 16B aligned)
__global__ __launch_bounds__(64) void groupnet_kernel(
    const float* __restrict__ pts,             // [B,3,N] f32
    const float* __restrict__ centf,           // ws [B,M,3] f32
    const __hip_bfloat16* __restrict__ fout,   // ws [B,N,HH] bf16
    const float* __restrict__ pw1, const float* __restrict__ pb1,
    const float* __restrict__ pw2, const float* __restrict__ pb2,
    const float* __restrict__ pw3, const float* __restrict__ pb3,
    float* __restrict__ outf)                  // d_out + B*M*3: [B,256,M] f32
{
    __shared__ unsigned int h2s[KK * H2SU];    // packed bf16 pairs, 9.2KB
    __shared__ int sels[KK];

    const int g = blockIdx.x;                  // b*M + m
    const int b = g >> 10, m = g & (MM - 1);
    const int lane = threadIdx.x;

    const float* pts_b = pts + (size_t)b * 3 * NN;
    const float cx = centf[(size_t)g * 3];
    const float cy = centf[(size_t)g * 3 + 1];
    const float cz = centf[(size_t)g * 3 + 2];

    // ---- 1) ball query: 4-deep software pipeline over 64-pt chunks ----
    int cnt = 0, first = 0;
    bool have_first = false;
    float fx[4], fy[4], fz[4];
#pragma unroll
    for (int q = 0; q < 4; ++q) {
        int p = q * 64 + lane;
        fx[q] = pts_b[p]; fy[q] = pts_b[NN + p]; fz[q] = pts_b[2 * NN + p];
    }
    for (int base = 0; base < NN; base += 256) {
#pragma unroll
        for (int q = 0; q < 4; ++q) {          // q static: regs stay in VGPRs
            const int cb = base + q * 64;      // this chunk's base
            float vx = fx[q], vy = fy[q], vz = fz[q];
            const int pre = cb + 256 + lane;   // prefetch 4 chunks ahead
            if (pre < NN) {
                fx[q] = pts_b[pre]; fy[q] = pts_b[NN + pre]; fz[q] = pts_b[2 * NN + pre];
            }
            float dx = vx - cx, dy = vy - cy, dz = vz - cz;
            float d2 = __fadd_rn(__fadd_rn(__fmul_rn(dx, dx), __fmul_rn(dy, dy)),
                                 __fmul_rn(dz, dz));
            bool in = (d2 <= R2F);
            unsigned long long mask = __ballot(in);
            if (!have_first && mask != 0ULL) {
                first = cb + (int)__builtin_ctzll(mask);
                have_first = true;
            }
            int pos = cnt + (int)__popcll(mask & ((1ULL << lane) - 1ULL));
            if (in && pos < KK) sels[pos] = cb + lane;
            cnt += (int)__popcll(mask);
        }
    }
    if (cnt < KK) {
        for (int q = cnt + lane; q < KK; q += 64) sels[q] = first;
    }
    __syncthreads();                           // sels visible

    const int s = sels[lane];
    float* ob = outf + (size_t)b * 256 * MM + m;

    // ---- 2) point path layers 1-2 (lane = slot k); 8 parallel chains ----
    {
        const float x = pts_b[s]          - cx;
        const float y = pts_b[NN + s]     - cy;
        const float z = pts_b[2 * NN + s] - cz;
        float h1[CIN];
#pragma unroll
        for (int o = 0; o < CIN; ++o) {
            float acc = pb1[o];
            acc = fmaf(x, pw1[o * 3 + 0], acc);
            acc = fmaf(y, pw1[o * 3 + 1], acc);
            acc = fmaf(z, pw1[o * 3 + 2], acc);
            h1[o] = fmaxf(acc, 0.f);
        }
        for (int o8 = 0; o8 < CIN / 8; ++o8) { // 8 outputs per iter
            float a[8];
#pragma unroll
            for (int q = 0; q < 8; ++q) a[q] = pb2[o8 * 8 + q];
            for (int c = 0; c < CIN; ++c) {
                float hc = h1[c];
#pragma unroll
                for (int q = 0; q < 8; ++q)
                    a[q] = fmaf(hc, pw2[(o8 * 8 + q) * CIN + c], a[q]);
            }
            uint4 pk;
            pk.x = bf16bits(fmaxf(a[0], 0.f)) | (bf16bits(fmaxf(a[1], 0.f)) << 16);
            pk.y = bf16bits(fmaxf(a[2], 0.f)) | (bf16bits(fmaxf(a[3], 0.f)) << 16);
            pk.z = bf16bits(fmaxf(a[4], 0.f)) | (bf16bits(fmaxf(a[5], 0.f)) << 16);
            pk.w = bf16bits(fmaxf(a[6], 0.f)) | (bf16bits(fmaxf(a[7], 0.f)) << 16);
            *(uint4*)&h2s[lane * H2SU + o8 * 4] = pk;
        }
    }
    __syncthreads();

    // ---- 3) point layer 3 + group max -> out ch 128..255 (k-split ILP) ----
    {
        float w3a[CIN], w3b[CIN];
#pragma unroll
        for (int c = 0; c < CIN; ++c) {
            w3a[c] = pw3[(size_t)lane * CIN + c];
            w3b[c] = pw3[(size_t)(lane + 64) * CIN + c];
        }
        const float b3a = pb3[lane], b3b = pb3[lane + 64];
        float pa0 = -3.4e38f, pb0 = -3.4e38f;  // k in [0,32)
        float pa1 = -3.4e38f, pb1v = -3.4e38f; // k in [32,64)
        for (int k = 0; k < KK / 2; ++k) {
            float va0 = b3a, vb0 = b3b, va1 = b3a, vb1 = b3b;
#pragma unroll
            for (int u4 = 0; u4 < 8; ++u4) {   // 8 uint4 = 32 u32 = 64 bf16
                uint4 p0 = *(const uint4*)&h2s[k * H2SU + u4 * 4];
                uint4 p1 = *(const uint4*)&h2s[(k + 32) * H2SU + u4 * 4];
                const unsigned int* w0 = &p0.x;
                const unsigned int* w1 = &p1.x;
#pragma unroll
                for (int j = 0; j < 4; ++j) {
                    int c = u4 * 8 + j * 2;
                    float h0lo = __uint_as_float(w0[j] << 16);
                    float h0hi = __uint_as_float(w0[j] & 0xFFFF0000u);
                    float h1lo = __uint_as_float(w1[j] << 16);
                    float h1hi = __uint_as_float(w1[j] & 0xFFFF0000u);
                    va0 = fmaf(h0lo, w3a[c],     va0); vb0 = fmaf(h0lo, w3b[c],     vb0);
                    va1 = fmaf(h1lo, w3a[c],     va1); vb1 = fmaf(h1lo, w3b[c],     vb1);
                    va0 = fmaf(h0hi, w3a[c + 1], va0); vb0 = fmaf(h0hi, w3b[c + 1], vb0);
                    va1 = fmaf(h1hi, w3a[c + 1], va1); vb1 = fmaf(h1hi, w3b[c + 1], vb1);
                }
            }
            pa0 = fmaxf(pa0, va0); pb0  = fmaxf(pb0,  vb0);
            pa1 = fmaxf(pa1, va1); pb1v = fmaxf(pb1v, vb1);
        }
        ob[(size_t)(128 + lane) * MM] = rnd_bf16(fmaxf(pa0, pa1));
        ob[(size_t)(192 + lane) * MM] = rnd_bf16(fmaxf(pb0, pb1v));
    }

    // ---- 4) feature gather-max (bf16 cache), u32 pair loads, 4-deep ----
    // lane owns channels (2*lane, 2*lane+1); max over same 64 rows -> exact.
    {
        const __hip_bfloat16* fb_ = fout + (size_t)b * NN * HH;
        unsigned int pf[4];
#pragma unroll
        for (int q = 0; q < 4; ++q)
            pf[q] = ((const unsigned int*)(fb_ + (size_t)sels[q] * HH))[lane];
        float alo[4], ahi[4];
#pragma unroll
        for (int q = 0; q < 4; ++q) { alo[q] = -3.4e38f; ahi[q] = -3.4e38f; }
        for (int k = 0; k < KK; k += 4) {
#pragma unroll
            for (int q = 0; q < 4; ++q) {      // q static: pf stays in VGPRs
                unsigned int w = pf[q];
                int nk = k + 4 + q;
                if (nk < KK)
                    pf[q] = ((const unsigned int*)(fb_ + (size_t)sels[nk] * HH))[lane];
                alo[q] = fmaxf(alo[q], __uint_as_float(w << 16));
                ahi[q] = fmaxf(ahi[q], __uint_as_float(w & 0xFFFF0000u));
            }
        }
        float lo = fmaxf(fmaxf(alo[0], alo[1]), fmaxf(alo[2], alo[3]));
        float hi = fmaxf(fmaxf(ahi[0], ahi[1]), fmaxf(ahi[2], ahi[3]));
        ob[(size_t)(2 * lane) * MM]     = lo;  // values already bf16-exact
        ob[(size_t)(2 * lane + 1) * MM] = hi;
    }
}

extern "C" void kernel_launch(void* const* d_in, const int* in_sizes, int n_in,
                              void* d_out, int out_size, void* d_ws, size_t ws_size,
                              hipStream_t stream) {
    const float* pts  = (const float*)d_in[0];
    const float* feat = (const float*)d_in[1];
    const float* pw1  = (const float*)d_in[2];
    const float* pb1  = (const float*)d_in[3];
    const float* pw2  = (const float*)d_in[4];
    const float* pb2  = (const float*)d_in[5];
    const float* pw3  = (const float*)d_in[6];
    const float* pb3  = (const float*)d_in[7];
    const float* fw1  = (const float*)d_in[8];
    const float* fb1  = (const float*)d_in[9];
    const float* fw2  = (const float*)d_in[10];
    const float* fb2  = (const float*)d_in[11];
    const float* fw3  = (const float*)d_in[12];
    const float* fb3  = (const float*)d_in[13];

    float* out = (float*)d_out;                // f32 output

    // ws: [0,96KB) f32 centroids; [96KB, +8.39MB) bf16 feature-MLP cache.
    float* centf = (float*)d_ws;
    __hip_bfloat16* fout = (__hip_bfloat16*)((char*)d_ws + (size_t)BB * MM * 3 * 4);

    // Merged launch: blocks 0..7 = FPS, blocks 8..135 = featmlp (runs
    // concurrently on otherwise-idle CUs; featmlp output is consumed only
    // by groupnet, which is stream-ordered after this dispatch).
    fps_featmlp_kernel<<<BB + (BB * NN) / 256, 256, 0, stream>>>(
        pts, centf, out, feat, fw1, fb1, fw2, fb2, fw3, fb3, fout);
    groupnet_kernel<<<BB * MM, 64, 0, stream>>>(
        pts, centf, fout,
        pw1, pb1, pw2, pb2, pw3, pb3,
        out + (size_t)BB * MM * 3);
}